// Round 9
// baseline (67.698 us; speedup 1.0000x reference)
//
#include <hip/hip_runtime.h>
#include <math.h>

#define N_NODES 65536
#define G_SEG   512
#define NE      256                 // L-grid intervals over [0,10] for xw lerp
#define XW_ELEMS ((NE + 1) * 300 * 64)  // 19.74 MB

// build_all roles
#define NB_B  300                   // one zm per block
#define NB_S  3                     // seg bounds
#define NB_P0 (N_NODES / 256)       // 256: per-node aux precompute
#define NB_ALL (NB_B + NB_S + NB_P0)

#define CH 4                        // chunks per segment in hot kernel

// ---------------------------------------------------------------------------
// build_all: fused preprocessing. Roles by blockIdx.x:
//  B (0..299):  for zm = b, compute feat -> T2[zm] (LDS) -> basis/Hs tables
//               (LDS, f32 __expf) -> xwtab[e][zm][j] = sum_m Hs[e][m]*T2[j][m]
//  S:           seg[g] = lower_bound(batch, g)
//  P0:          aux[i] = (ux, uy, uz, pack(e, zmi, frac14))
// ---------------------------------------------------------------------------
__global__ __launch_bounds__(256) void build_all(
    const float* __restrict__ emb_z, const float* __restrict__ emb_mol,
    const float* __restrict__ W2, const float* __restrict__ W1,
    const int* __restrict__ batch,
    const float* __restrict__ pos, const int* __restrict__ xz,
    const int* __restrict__ mol,
    float* __restrict__ xwtab, int* __restrict__ seg,
    float4* __restrict__ aux, float silu_c)
{
    __shared__ float feat[64];
    __shared__ float w1s[320];
    __shared__ float t2s[64 * 36];      // [j][m], pad 36 (16B-aligned rows, conflict-light)
    __shared__ float ebas[2570 + 2];    // [e][k], 257 x 10
    __shared__ float hs[257 * 32];      // [e][m]

    const int b = blockIdx.x;
    const int t = threadIdx.x;

    if (b < NB_B) {
        const int zm = b;
        const int z  = zm / 3, mo = zm % 3;

        // ---- phase 1: feat + W1 into LDS
        if (t < 48)      feat[t] = emb_z[z * 48 + t];
        else if (t < 64) feat[t] = emb_mol[mo * 16 + (t - 48)];
        for (int p = t; p < 320; p += 256) w1s[p] = W1[p];
        __syncthreads();

        // ---- phase 2: T2[zm][j][m] into LDS (j = l*16+wi)
        {
            const float scale = 0.02209708691207961f;  // 1/sqrt(2048)
            const int wi  = t & 15;
            const int mlo = t >> 4;
#pragma unroll
            for (int l = 0; l < 4; ++l) {
#pragma unroll
                for (int i = 0; i < 2; ++i) {
                    const int m = mlo + 16 * i;
                    const float* w2p = W2 + m * 4096 + l * 1024 + wi;
                    float acc = 0.f;
#pragma unroll 8
                    for (int u = 0; u < 64; ++u)
                        acc = fmaf(feat[u], w2p[u * 16], acc);
                    t2s[(l * 16 + wi) * 36 + m] = acc * scale;
                }
            }
        }

        // ---- phase 3: basis table ebas[e][k], e = 0..256, f32
        {
            const float c = 8.4335412f;   // 1.14136 * e^2
            for (int p = t; p < 2570; p += 256) {
                const int e = p / 10, k = p - 10 * e;
                const float L = (float)e * (10.f / (float)NE);
                const float a  = 1.1f * L - (float)k;
                const float bb = (float)(k + 2) - 1.1f * L;
                // exp(-1/a)*exp(-1/b) = exp(-2/(ab)) since a+b == 2
                ebas[p] = (a > 0.f && bb > 0.f) ? c * __expf(-2.f / (a * bb)) : 0.f;
            }
        }
        __syncthreads();

        // ---- phase 4: Hs[e][m] = silu_c * silu( sum_k ebas[e][k] * W1[k][m] )
        for (int p = t; p < 257 * 32; p += 256) {
            const int e = p >> 5, m = p & 31;
            float s = 0.f;
#pragma unroll
            for (int k = 0; k < 10; ++k)
                s = fmaf(ebas[e * 10 + k], w1s[k * 32 + m], s);
            hs[p] = silu_c * s / (1.f + __expf(-s));
        }
        __syncthreads();

        // ---- phase 5: xwtab[e][zm][j] = sum_m hs[e][m] * t2s[j][m]
        {
            const int j = t & 63;
            const int w = t >> 6;
            float tr[32];
            const float* trow = &t2s[j * 36];
#pragma unroll
            for (int q = 0; q < 8; ++q) {
                const float4 v = *reinterpret_cast<const float4*>(trow + 4 * q);
                tr[4 * q] = v.x; tr[4 * q + 1] = v.y; tr[4 * q + 2] = v.z; tr[4 * q + 3] = v.w;
            }
            for (int e = w; e <= NE; e += 4) {
                const float4* hrow = reinterpret_cast<const float4*>(&hs[e * 32]);
                float a0 = 0.f, a1 = 0.f, a2 = 0.f, a3 = 0.f;
#pragma unroll
                for (int q = 0; q < 8; ++q) {
                    const float4 h4 = hrow[q];     // wave-uniform -> broadcast
                    a0 = fmaf(h4.x, tr[4 * q + 0], a0);
                    a1 = fmaf(h4.y, tr[4 * q + 1], a1);
                    a2 = fmaf(h4.z, tr[4 * q + 2], a2);
                    a3 = fmaf(h4.w, tr[4 * q + 3], a3);
                }
                xwtab[((e * 300 + zm) << 6) + j] = (a0 + a1) + (a2 + a3);
            }
        }
    } else if (b < NB_B + NB_S) {
        const int g = (b - NB_B) * 256 + t;
        if (g > G_SEG) return;
        int lo = 0, hi = N_NODES;
        while (lo < hi) {
            const int mid = (lo + hi) >> 1;
            if (batch[mid] < g) lo = mid + 1; else hi = mid;
        }
        seg[g] = lo;
    } else {
        const int i = (b - NB_B - NB_S) * 256 + t;
        const float px = pos[3 * i], py = pos[3 * i + 1], pz = pos[3 * i + 2];
        const int zmi = xz[i] * 3 + mol[i];
        const float Lsq = px * px + py * py + pz * pz;
        const float rinv = __builtin_amdgcn_rsqf(Lsq);
        const float L = Lsq * rinv;
        const float tt = fminf(L * ((float)NE / 10.0f), 255.999f);
        const int e = (int)tt;
        const int fr14 = min((int)((tt - (float)e) * 16384.f), 16383);
        float4 a;
        a.x = px * rinv; a.y = py * rinv; a.z = pz * rinv;
        a.w = __uint_as_float(((unsigned)e << 23) | ((unsigned)zmi << 14) | (unsigned)fr14);
        aux[i] = a;
    }
}

// ---------------------------------------------------------------------------
// seg_xw: CH blocks per segment, 256 thr = 4 waves, ~8 nodes/wave.
// 1-stage software pipeline: aux + lerp-row loads for iteration i+1 issue
// before iteration i's SH math. Plain partial store (no atomics).
// Lane j = l*16+wi owns output slots [off + wi*(2l+1) .. +2l].
// ---------------------------------------------------------------------------
__global__ __launch_bounds__(256) void seg_xw(
    const float4* __restrict__ aux, const int* __restrict__ seg,
    const float* __restrict__ xwtab, float* __restrict__ partials)
{
    __shared__ float red[4 * 257];

    const int g = blockIdx.x >> 2;
    const int c = blockIdx.x & 3;
    const int s0 = seg[g], s1 = seg[g + 1];
    const int cnt = s1 - s0;
    const int q0 = s0 + (cnt * c) / CH;
    const int q1 = s0 + (cnt * (c + 1)) / CH;

    const int w    = threadIdx.x >> 6;
    const int lane = threadIdx.x & 63;

    const int l  = lane >> 4;
    const int wi = lane & 15;
    const int nl = 2 * l + 1;
    const int off = (l == 0 ? 0 : (l == 1 ? 16 : (l == 2 ? 64 : 144)));
    const int base = off + wi * nl;

    float acc[7];
#pragma unroll
    for (int k = 0; k < 7; ++k) acc[k] = 0.f;

    int i = q0 + w;
    float4 aN = make_float4(0.f, 0.f, 1.f, __uint_as_float(0u));
    float f0N = 0.f, f1N = 0.f;
    if (i < q1) {
        aN = aux[i];
        const unsigned code = __float_as_uint(aN.w);
        const float* r = xwtab + ((int)(code >> 23) * 300 + (int)((code >> 14) & 511u)) * 64 + lane;
        f0N = r[0]; f1N = r[300 * 64];
    }

    for (; i < q1; i += 4) {
        const float4 a = aN;
        const float f0 = f0N, f1 = f1N;

        // prefetch next iteration's aux + rows
        const int in = i + 4;
        if (in < q1) {
            aN = aux[in];
            const unsigned cn = __float_as_uint(aN.w);
            const float* rn = xwtab + ((int)(cn >> 23) * 300 + (int)((cn >> 14) & 511u)) * 64 + lane;
            f0N = rn[0]; f1N = rn[300 * 64];
        }

        const unsigned code = __float_as_uint(a.w);
        const float fr = (float)(code & 16383u) * 6.103515625e-5f;  // /16384
        const float xwv = fmaf(fr, f1 - f0, f0);

        // spherical harmonics (component normalization)
        const float ux = a.x, uy = a.y, uz = a.z;
        const float s3 = 1.7320508075688772f, s5 = 2.2360679774997896f, s7 = 2.6457513110645907f;
        const float y2 = uy * uy, x2z2 = ux * ux + uz * uz;
        const float s20 = s3 * ux * uz;
        const float s21 = s3 * ux * uy;
        const float s22 = y2 - 0.5f * x2z2;
        const float s23 = s3 * uy * uz;
        const float s24 = 0.5f * s3 * (uz * uz - ux * ux);

        float shv[7];
#pragma unroll
        for (int k = 0; k < 7; ++k) shv[k] = 0.f;
        if (l == 0) {
            shv[0] = 1.f;
        } else if (l == 1) {
            shv[0] = s3 * ux; shv[1] = s3 * uy; shv[2] = s3 * uz;
        } else if (l == 2) {
            shv[0] = s5 * s20; shv[1] = s5 * s21; shv[2] = s5 * s22;
            shv[3] = s5 * s23; shv[4] = s5 * s24;
        } else {
            const float c56 = 0.9128709291752769f;  // sqrt(5/6)
            const float c38 = 0.6123724356957945f;  // sqrt(3/8)
            const float s30 = c56 * (s20 * uz + s24 * ux);
            const float s31 = s5 * s20 * uy;
            const float s32 = c38 * (4.f * y2 - x2z2) * ux;
            const float s33 = 0.5f * uy * (2.f * y2 - 3.f * x2z2);
            const float s34 = c38 * uz * (4.f * y2 - x2z2);
            const float s35 = s5 * s24 * uy;
            const float s36 = c56 * (s24 * uz - s20 * ux);
            shv[0] = s7 * s30; shv[1] = s7 * s31; shv[2] = s7 * s32;
            shv[3] = s7 * s33; shv[4] = s7 * s34; shv[5] = s7 * s35; shv[6] = s7 * s36;
        }

#pragma unroll
        for (int k = 0; k < 7; ++k)
            if (k < nl) acc[k] = fmaf(xwv, shv[k], acc[k]);
    }

    // block reduction across 4 waves, then one plain coalesced partial store
#pragma unroll
    for (int k = 0; k < 7; ++k)
        if (k < nl) red[w * 257 + base + k] = acc[k];
    __syncthreads();

    if (threadIdx.x < 256) {
        float s = 0.f;
#pragma unroll
        for (int ww = 0; ww < 4; ++ww) s += red[ww * 257 + threadIdx.x];
        partials[blockIdx.x * 256 + threadIdx.x] = s;
    }
}

// ---------------------------------------------------------------------------
// reduce: out[g][t] = (1/cnt) * sum_c partials[g*CH+c][t]
// ---------------------------------------------------------------------------
__global__ __launch_bounds__(256) void reduce(
    const float* __restrict__ partials, const int* __restrict__ seg,
    float* __restrict__ out)
{
    const int g = blockIdx.x;
    const int t = threadIdx.x;
    const int cnt = seg[g + 1] - seg[g];
    float s = 0.f;
#pragma unroll
    for (int c = 0; c < CH; ++c)
        s += partials[(g * CH + c) * 256 + t];
    out[g * 256 + t] = s / (float)max(cnt, 1);
}

// ---------------------------------------------------------------------------
static double silu_c_host()
{
    const int n = 200001;
    const double h = 24.0 / 200000.0;
    double sum = 0.0, prev = 0.0;
    for (int i = 0; i < n; ++i) {
        const double z = -12.0 + h * (double)i;
        const double pdf = exp(-0.5 * z * z) * 0.3989422804014327;
        const double s = z / (1.0 + exp(-z));
        const double f = s * s * pdf;
        if (i) sum += prev + f;
        prev = f;
    }
    sum *= 0.5 * h;
    return 1.0 / sqrt(sum);
}

extern "C" void kernel_launch(void* const* d_in, const int* in_sizes, int n_in,
                              void* d_out, int out_size, void* d_ws, size_t ws_size,
                              hipStream_t stream)
{
    const float* pos     = (const float*)d_in[0];
    const int*   xz      = (const int*)d_in[1];
    const int*   mol     = (const int*)d_in[2];
    const int*   batch   = (const int*)d_in[3];
    const float* emb_z   = (const float*)d_in[4];
    const float* emb_mol = (const float*)d_in[5];
    const float* W1      = (const float*)d_in[6];
    const float* W2      = (const float*)d_in[7];
    float* out = (float*)d_out;

    // workspace layout (floats): seg(1024 ints) | aux | xwtab | partials ~= 23.3 MB
    int*    seg   = (int*)d_ws;
    float4* aux   = (float4*)((float*)d_ws + 1024);
    float*  xwtab = (float*)aux + 4 * N_NODES;
    float*  parts = xwtab + XW_ELEMS;                 // 512*CH*256 floats = 2 MB

    static const float SILU_C_F = (float)silu_c_host();

    build_all<<<NB_ALL, 256, 0, stream>>>(emb_z, emb_mol, W2, W1, batch,
                                          pos, xz, mol, xwtab, seg, aux, SILU_C_F);
    seg_xw<<<G_SEG * CH, 256, 0, stream>>>(aux, seg, xwtab, parts);
    reduce<<<G_SEG, 256, 0, stream>>>(parts, seg, out);
}

// Round 10
// 43.617 us; speedup vs baseline: 1.5521x; 1.5521x over previous
//
#include <hip/hip_runtime.h>
#include <math.h>

#define N_NODES 65536
#define G_SEG   512
#define NE      256                  // L-grid intervals over [0,10] for xw lerp

// build_AB roles
#define NB_E  257                    // one e-slice per block
#define NB_S  3                      // seg bounds
#define NB_P0 (N_NODES / 256)        // 256: per-node aux precompute
#define NB_ALL (NB_E + NB_S + NB_P0) // 516

#define CH 4                         // chunks per segment in hot kernel

#define A_ELEMS (257 * 100 * 64)     // 6.58 MB
#define B_ELEMS (257 * 3 * 64)       // 197 KB

// ---------------------------------------------------------------------------
// build_AB: roles by blockIdx.x.
//  E (0..256):   for e = b: compute hs[e][m] (f32) -> W2h[u][j] in LDS
//                (= sum_m hs[m] * W2r[u][j][m], scale folded) ->
//                A[e][z][j] = sum_{u<48} emb_z[z][u]*W2h[u][j]  (100x64)
//                B[e][mo][j] = sum_{u<16} emb_mol[mo][u]*W2h[48+u][j]  (3x64)
//  S:            seg[g] = lower_bound(batch, g)
//  P0:           aux[i] = (ux, uy, uz, pack(e8, z7, mo2, fr15))
// ---------------------------------------------------------------------------
__global__ __launch_bounds__(256) void build_AB(
    const float* __restrict__ emb_z, const float* __restrict__ emb_mol,
    const float* __restrict__ W2, const float* __restrict__ W1,
    const int* __restrict__ batch,
    const float* __restrict__ pos, const int* __restrict__ xz,
    const int* __restrict__ mol,
    float* __restrict__ A, float* __restrict__ B,
    int* __restrict__ seg, float4* __restrict__ aux, float silu_c)
{
    __shared__ float w2h[64 * 64];     // [u][j]
    __shared__ float ezs[100 * 48];    // emb_z staged
    __shared__ float emol[48];
    __shared__ float hsrow[32];

    const int b = blockIdx.x;
    const int t = threadIdx.x;

    if (b < NB_E) {
        const int e = b;

        // stage emb_z / emb_mol; threads t<32 also compute the hs row
        for (int p = t; p < 4800; p += 256) ezs[p] = emb_z[p];
        if (t < 48) emol[t] = emb_mol[t];
        if (t < 32) {
            const int m = t;
            const float L = (float)e * (10.f / (float)NE);
            const float c = 8.4335412f;    // 1.14136 * exp(2)
            float p = 0.f;
#pragma unroll
            for (int k = 0; k < 10; ++k) {
                const float a  = 1.1f * L - (float)k;
                const float bb = (float)(k + 2) - 1.1f * L;
                // exp(-1/a)*exp(-1/b) = exp(-2/(ab)) since a+b == 2
                const float bas = (a > 0.f && bb > 0.f) ? c * __expf(-2.f / (a * bb)) : 0.f;
                p = fmaf(bas, W1[k * 32 + m], p);
            }
            hsrow[m] = silu_c * p / (1.f + __expf(-p));
        }
        __syncthreads();

        // ---- phase A: W2h[u][j] = scale * sum_m hsrow[m] * W2[m][l*1024+u*16+wi]
        {
            const int j  = t & 63;
            const int l  = j >> 4, wi = j & 15;
            const int u0 = (t >> 6) * 16;          // wave's u range
            const float scale = 0.02209708691207961f;  // 1/sqrt(2048)
            float acc[16];
#pragma unroll
            for (int q = 0; q < 16; ++q) acc[q] = 0.f;
            const float* wbase = W2 + l * 1024 + wi + u0 * 16;
            for (int m = 0; m < 32; ++m) {
                const float h = hsrow[m];
                const float* wp = wbase + m * 4096;
#pragma unroll
                for (int q = 0; q < 16; ++q)
                    acc[q] = fmaf(h, wp[q * 16], acc[q]);
            }
#pragma unroll
            for (int q = 0; q < 16; ++q)
                w2h[(u0 + q) * 64 + j] = acc[q] * scale;
        }
        __syncthreads();

        // ---- phase B: A[e][z][j] (z = zg+4*zi) and B[e][mo][j]
        {
            const int j  = t & 63;
            const int zg = t >> 6;
            float accz[25];
#pragma unroll
            for (int zi = 0; zi < 25; ++zi) accz[zi] = 0.f;
            for (int ut = 0; ut < 48; ut += 8) {
                float wr[8];
#pragma unroll
                for (int q = 0; q < 8; ++q) wr[q] = w2h[(ut + q) * 64 + j];
#pragma unroll
                for (int zi = 0; zi < 25; ++zi) {
                    const int z = zg + 4 * zi;
#pragma unroll
                    for (int q = 0; q < 8; ++q)
                        accz[zi] = fmaf(ezs[z * 48 + ut + q], wr[q], accz[zi]);
                }
            }
#pragma unroll
            for (int zi = 0; zi < 25; ++zi)
                A[((e * 100 + zg + 4 * zi) << 6) + j] = accz[zi];

            if (t < 192) {
                const int mo = t >> 6;
                float s = 0.f;
#pragma unroll
                for (int q = 0; q < 16; ++q)
                    s = fmaf(emol[mo * 16 + q], w2h[(48 + q) * 64 + j], s);
                B[((e * 3 + mo) << 6) + j] = s;
            }
        }
    } else if (b < NB_E + NB_S) {
        const int g = (b - NB_E) * 256 + t;
        if (g > G_SEG) return;
        int lo = 0, hi = N_NODES;
        while (lo < hi) {
            const int mid = (lo + hi) >> 1;
            if (batch[mid] < g) lo = mid + 1; else hi = mid;
        }
        seg[g] = lo;
    } else {
        const int i = (b - NB_E - NB_S) * 256 + t;
        const float px = pos[3 * i], py = pos[3 * i + 1], pz = pos[3 * i + 2];
        const int z  = xz[i];
        const int mo = mol[i];
        const float Lsq = px * px + py * py + pz * pz;
        const float rinv = __builtin_amdgcn_rsqf(Lsq);
        const float L = Lsq * rinv;
        const float tt = fminf(L * ((float)NE / 10.0f), 255.999f);
        const int e = (int)tt;
        const int fr15 = min((int)((tt - (float)e) * 32768.f), 32767);
        float4 a;
        a.x = px * rinv; a.y = py * rinv; a.z = pz * rinv;
        a.w = __uint_as_float(((unsigned)e << 24) | ((unsigned)z << 17) |
                              ((unsigned)mo << 15) | (unsigned)fr15);
        aux[i] = a;
    }
}

// ---------------------------------------------------------------------------
// seg_xw: CH blocks per segment, 256 thr = 4 waves. Per node: broadcast aux
// load + 4 lerp-row dwords per lane (A rows from 6.6MB L2-resident table,
// B rows from 197KB L1-hot table). 1-stage prefetch pipeline. Plain partial
// store. Lane j = l*16+wi owns output slots [off + wi*(2l+1) .. +2l].
// ---------------------------------------------------------------------------
__global__ __launch_bounds__(256) void seg_xw(
    const float4* __restrict__ aux, const int* __restrict__ seg,
    const float* __restrict__ A, const float* __restrict__ B,
    float* __restrict__ partials)
{
    __shared__ float red[4 * 257];

    const int g = blockIdx.x >> 2;
    const int c = blockIdx.x & 3;
    const int s0 = seg[g], s1 = seg[g + 1];
    const int cnt = s1 - s0;
    const int q0 = s0 + (cnt * c) / CH;
    const int q1 = s0 + (cnt * (c + 1)) / CH;

    const int w    = threadIdx.x >> 6;
    const int lane = threadIdx.x & 63;

    const int l  = lane >> 4;
    const int wi = lane & 15;
    const int nl = 2 * l + 1;
    const int off = (l == 0 ? 0 : (l == 1 ? 16 : (l == 2 ? 64 : 144)));
    const int base = off + wi * nl;

    float acc[7];
#pragma unroll
    for (int k = 0; k < 7; ++k) acc[k] = 0.f;

    int i = q0 + w;
    float4 aN = make_float4(0.f, 0.f, 1.f, __uint_as_float(0u));
    float a0N = 0.f, a1N = 0.f, b0N = 0.f, b1N = 0.f;
    if (i < q1) {
        aN = aux[i];
        const unsigned cd = __float_as_uint(aN.w);
        const float* Ar = A + (((cd >> 24) * 100 + ((cd >> 17) & 127u)) << 6) + lane;
        const float* Br = B + (((cd >> 24) * 3 + ((cd >> 15) & 3u)) << 6) + lane;
        a0N = Ar[0]; a1N = Ar[6400]; b0N = Br[0]; b1N = Br[192];
    }

    for (; i < q1; i += 4) {
        const float4 a = aN;
        const float f0 = a0N + b0N, f1 = a1N + b1N;

        // prefetch next iteration
        const int in = i + 4;
        if (in < q1) {
            aN = aux[in];
            const unsigned cn = __float_as_uint(aN.w);
            const float* Ar = A + (((cn >> 24) * 100 + ((cn >> 17) & 127u)) << 6) + lane;
            const float* Br = B + (((cn >> 24) * 3 + ((cn >> 15) & 3u)) << 6) + lane;
            a0N = Ar[0]; a1N = Ar[6400]; b0N = Br[0]; b1N = Br[192];
        }

        const unsigned code = __float_as_uint(a.w);
        const float fr = (float)(code & 32767u) * 3.0517578125e-5f;  // /32768
        const float xwv = fmaf(fr, f1 - f0, f0);

        // spherical harmonics (component normalization)
        const float ux = a.x, uy = a.y, uz = a.z;
        const float s3 = 1.7320508075688772f, s5 = 2.2360679774997896f, s7 = 2.6457513110645907f;
        const float y2 = uy * uy, x2z2 = ux * ux + uz * uz;
        const float s20 = s3 * ux * uz;
        const float s21 = s3 * ux * uy;
        const float s22 = y2 - 0.5f * x2z2;
        const float s23 = s3 * uy * uz;
        const float s24 = 0.5f * s3 * (uz * uz - ux * ux);

        float shv[7];
#pragma unroll
        for (int k = 0; k < 7; ++k) shv[k] = 0.f;
        if (l == 0) {
            shv[0] = 1.f;
        } else if (l == 1) {
            shv[0] = s3 * ux; shv[1] = s3 * uy; shv[2] = s3 * uz;
        } else if (l == 2) {
            shv[0] = s5 * s20; shv[1] = s5 * s21; shv[2] = s5 * s22;
            shv[3] = s5 * s23; shv[4] = s5 * s24;
        } else {
            const float c56 = 0.9128709291752769f;  // sqrt(5/6)
            const float c38 = 0.6123724356957945f;  // sqrt(3/8)
            const float s30 = c56 * (s20 * uz + s24 * ux);
            const float s31 = s5 * s20 * uy;
            const float s32 = c38 * (4.f * y2 - x2z2) * ux;
            const float s33 = 0.5f * uy * (2.f * y2 - 3.f * x2z2);
            const float s34 = c38 * uz * (4.f * y2 - x2z2);
            const float s35 = s5 * s24 * uy;
            const float s36 = c56 * (s24 * uz - s20 * ux);
            shv[0] = s7 * s30; shv[1] = s7 * s31; shv[2] = s7 * s32;
            shv[3] = s7 * s33; shv[4] = s7 * s34; shv[5] = s7 * s35; shv[6] = s7 * s36;
        }

#pragma unroll
        for (int k = 0; k < 7; ++k)
            if (k < nl) acc[k] = fmaf(xwv, shv[k], acc[k]);
    }

    // block reduction across 4 waves, then one plain coalesced partial store
#pragma unroll
    for (int k = 0; k < 7; ++k)
        if (k < nl) red[w * 257 + base + k] = acc[k];
    __syncthreads();

    if (threadIdx.x < 256) {
        float s = 0.f;
#pragma unroll
        for (int ww = 0; ww < 4; ++ww) s += red[ww * 257 + threadIdx.x];
        partials[blockIdx.x * 256 + threadIdx.x] = s;
    }
}

// ---------------------------------------------------------------------------
// reduce: out[g][t] = (1/cnt) * sum_c partials[g*CH+c][t]
// ---------------------------------------------------------------------------
__global__ __launch_bounds__(256) void reduce(
    const float* __restrict__ partials, const int* __restrict__ seg,
    float* __restrict__ out)
{
    const int g = blockIdx.x;
    const int t = threadIdx.x;
    const int cnt = seg[g + 1] - seg[g];
    float s = 0.f;
#pragma unroll
    for (int c = 0; c < CH; ++c)
        s += partials[(g * CH + c) * 256 + t];
    out[g * 256 + t] = s / (float)max(cnt, 1);
}

// ---------------------------------------------------------------------------
static double silu_c_host()
{
    const int n = 200001;
    const double h = 24.0 / 200000.0;
    double sum = 0.0, prev = 0.0;
    for (int i = 0; i < n; ++i) {
        const double z = -12.0 + h * (double)i;
        const double pdf = exp(-0.5 * z * z) * 0.3989422804014327;
        const double s = z / (1.0 + exp(-z));
        const double f = s * s * pdf;
        if (i) sum += prev + f;
        prev = f;
    }
    sum *= 0.5 * h;
    return 1.0 / sqrt(sum);
}

extern "C" void kernel_launch(void* const* d_in, const int* in_sizes, int n_in,
                              void* d_out, int out_size, void* d_ws, size_t ws_size,
                              hipStream_t stream)
{
    const float* pos     = (const float*)d_in[0];
    const int*   xz      = (const int*)d_in[1];
    const int*   mol     = (const int*)d_in[2];
    const int*   batch   = (const int*)d_in[3];
    const float* emb_z   = (const float*)d_in[4];
    const float* emb_mol = (const float*)d_in[5];
    const float* W1      = (const float*)d_in[6];
    const float* W2      = (const float*)d_in[7];
    float* out = (float*)d_out;

    // workspace layout (floats): A | B | seg(1024 ints) | aux | partials ~= 9.9 MB
    float*  Abuf  = (float*)d_ws;
    float*  Bbuf  = Abuf + A_ELEMS;
    int*    seg   = (int*)(Bbuf + B_ELEMS);
    float4* aux   = (float4*)((float*)seg + 1024);
    float*  parts = (float*)aux + 4 * N_NODES;

    static const float SILU_C_F = (float)silu_c_host();

    build_AB<<<NB_ALL, 256, 0, stream>>>(emb_z, emb_mol, W2, W1, batch,
                                         pos, xz, mol, Abuf, Bbuf, seg, aux, SILU_C_F);
    seg_xw<<<G_SEG * CH, 256, 0, stream>>>(aux, seg, Abuf, Bbuf, parts);
    reduce<<<G_SEG, 256, 0, stream>>>(parts, seg, out);
}

// Round 12
// 39.611 us; speedup vs baseline: 1.7091x; 1.1011x over previous
//
#include <hip/hip_runtime.h>
#include <math.h>

#define N_NODES 65536
#define G_SEG   512
#define NE      256                  // L-grid intervals over [0,10] for xw lerp

// build_AB roles
#define NB_E  257                    // one e-slice per block
#define NB_S  3                      // seg bounds
#define NB_P0 (N_NODES / 256)        // 256: per-node aux precompute
#define NB_ALL (NB_E + NB_S + NB_P0) // 516

#define CH 4                         // chunks per segment in hot kernel

#define A_ELEMS (257 * 100 * 64)     // 6.58 MB
#define B_ELEMS (257 * 3 * 64)       // 197 KB

// ---------------------------------------------------------------------------
// build_AB: roles by blockIdx.x.  (unchanged from round 10)
//  E (0..256):   for e = b: hs[e][m] -> W2h[u][j] in LDS -> A[e][z][j], B[e][mo][j]
//  S:            seg[g] = lower_bound(batch, g)
//  P0:           aux[i] = (ux, uy, uz, pack(e8, z7, mo2, fr15))
// ---------------------------------------------------------------------------
__global__ __launch_bounds__(256) void build_AB(
    const float* __restrict__ emb_z, const float* __restrict__ emb_mol,
    const float* __restrict__ W2, const float* __restrict__ W1,
    const int* __restrict__ batch,
    const float* __restrict__ pos, const int* __restrict__ xz,
    const int* __restrict__ mol,
    float* __restrict__ A, float* __restrict__ B,
    int* __restrict__ seg, float4* __restrict__ aux, float silu_c)
{
    __shared__ float w2h[64 * 64];     // [u][j]
    __shared__ float ezs[100 * 48];    // emb_z staged
    __shared__ float emol[48];
    __shared__ float hsrow[32];

    const int b = blockIdx.x;
    const int t = threadIdx.x;

    if (b < NB_E) {
        const int e = b;

        for (int p = t; p < 4800; p += 256) ezs[p] = emb_z[p];
        if (t < 48) emol[t] = emb_mol[t];
        if (t < 32) {
            const int m = t;
            const float L = (float)e * (10.f / (float)NE);
            const float c = 8.4335412f;    // 1.14136 * exp(2)
            float p = 0.f;
#pragma unroll
            for (int k = 0; k < 10; ++k) {
                const float a  = 1.1f * L - (float)k;
                const float bb = (float)(k + 2) - 1.1f * L;
                // exp(-1/a)*exp(-1/b) = exp(-2/(ab)) since a+b == 2
                const float bas = (a > 0.f && bb > 0.f) ? c * __expf(-2.f / (a * bb)) : 0.f;
                p = fmaf(bas, W1[k * 32 + m], p);
            }
            hsrow[m] = silu_c * p / (1.f + __expf(-p));
        }
        __syncthreads();

        // phase A: W2h[u][j] = scale * sum_m hsrow[m] * W2[m][l*1024+u*16+wi]
        {
            const int j  = t & 63;
            const int l  = j >> 4, wi = j & 15;
            const int u0 = (t >> 6) * 16;
            const float scale = 0.02209708691207961f;  // 1/sqrt(2048)
            float acc[16];
#pragma unroll
            for (int q = 0; q < 16; ++q) acc[q] = 0.f;
            const float* wbase = W2 + l * 1024 + wi + u0 * 16;
            for (int m = 0; m < 32; ++m) {
                const float h = hsrow[m];
                const float* wp = wbase + m * 4096;
#pragma unroll
                for (int q = 0; q < 16; ++q)
                    acc[q] = fmaf(h, wp[q * 16], acc[q]);
            }
#pragma unroll
            for (int q = 0; q < 16; ++q)
                w2h[(u0 + q) * 64 + j] = acc[q] * scale;
        }
        __syncthreads();

        // phase B: A[e][z][j] and B[e][mo][j]
        {
            const int j  = t & 63;
            const int zg = t >> 6;
            float accz[25];
#pragma unroll
            for (int zi = 0; zi < 25; ++zi) accz[zi] = 0.f;
            for (int ut = 0; ut < 48; ut += 8) {
                float wr[8];
#pragma unroll
                for (int q = 0; q < 8; ++q) wr[q] = w2h[(ut + q) * 64 + j];
#pragma unroll
                for (int zi = 0; zi < 25; ++zi) {
                    const int z = zg + 4 * zi;
#pragma unroll
                    for (int q = 0; q < 8; ++q)
                        accz[zi] = fmaf(ezs[z * 48 + ut + q], wr[q], accz[zi]);
                }
            }
#pragma unroll
            for (int zi = 0; zi < 25; ++zi)
                A[((e * 100 + zg + 4 * zi) << 6) + j] = accz[zi];

            if (t < 192) {
                const int mo = t >> 6;
                float s = 0.f;
#pragma unroll
                for (int q = 0; q < 16; ++q)
                    s = fmaf(emol[mo * 16 + q], w2h[(48 + q) * 64 + j], s);
                B[((e * 3 + mo) << 6) + j] = s;
            }
        }
    } else if (b < NB_E + NB_S) {
        const int g = (b - NB_E) * 256 + t;
        if (g > G_SEG) return;
        int lo = 0, hi = N_NODES;
        while (lo < hi) {
            const int mid = (lo + hi) >> 1;
            if (batch[mid] < g) lo = mid + 1; else hi = mid;
        }
        seg[g] = lo;
    } else {
        const int i = (b - NB_E - NB_S) * 256 + t;
        const float px = pos[3 * i], py = pos[3 * i + 1], pz = pos[3 * i + 2];
        const int z  = xz[i];
        const int mo = mol[i];
        const float Lsq = px * px + py * py + pz * pz;
        const float rinv = __builtin_amdgcn_rsqf(Lsq);
        const float L = Lsq * rinv;
        const float tt = fminf(L * ((float)NE / 10.0f), 255.999f);
        const int e = (int)tt;
        const int fr15 = min((int)((tt - (float)e) * 32768.f), 32767);
        float4 a;
        a.x = px * rinv; a.y = py * rinv; a.z = pz * rinv;
        a.w = __uint_as_float(((unsigned)e << 24) | ((unsigned)z << 17) |
                              ((unsigned)mo << 15) | (unsigned)fr15);
        aux[i] = a;
    }
}

// ---------------------------------------------------------------------------
// seg_xw: CH blocks per segment, 256 thr = 4 waves. WAVE w OWNS l = w:
// the SH branch is wave-uniform and each wave-iteration covers 4 nodes
// (lane = ns*16+wi). Block reduce uses red[4][257] with ROW = ns: the four
// waves write DISJOINT column ranges (l=0: 0-15, l=1: 16-63, l=2: 64-143,
// l=3: 144-255), so every column of every row is written exactly once --
// full coverage, no stale-LDS garbage (round-11 bug). Plain partial store.
// ---------------------------------------------------------------------------
__global__ __launch_bounds__(256) void seg_xw(
    const float4* __restrict__ aux, const int* __restrict__ seg,
    const float* __restrict__ A, const float* __restrict__ B,
    float* __restrict__ partials)
{
    __shared__ float red[4 * 257];

    const int g = blockIdx.x >> 2;
    const int c = blockIdx.x & 3;
    const int s0 = seg[g], s1 = seg[g + 1];
    const int cnt = s1 - s0;
    const int q0 = s0 + (cnt * c) / CH;
    const int q1 = s0 + (cnt * (c + 1)) / CH;

    const int l    = __builtin_amdgcn_readfirstlane(threadIdx.x >> 6);  // wave = l
    const int lane = threadIdx.x & 63;
    const int ns   = lane >> 4;
    const int wi   = lane & 15;
    const int jj   = l * 16 + wi;          // column into A/B rows

    float acc[7];
#pragma unroll
    for (int k = 0; k < 7; ++k) acc[k] = 0.f;

    const int niter = (q1 - q0 + 3) >> 2;  // wave-uniform

    float4 aN = make_float4(0.f, 0.f, 1.f, __uint_as_float(0u));
    float a0N = 0.f, a1N = 0.f, b0N = 0.f, b1N = 0.f;
    if (niter > 0) {
        const int ic = min(q0 + ns, q1 - 1);
        aN = aux[ic];
        const unsigned cd = __float_as_uint(aN.w);
        const float* Ar = A + (((cd >> 24) * 100 + ((cd >> 17) & 127u)) << 6) + jj;
        const float* Br = B + (((cd >> 24) * 3 + ((cd >> 15) & 3u)) << 6) + jj;
        a0N = Ar[0]; a1N = Ar[6400]; b0N = Br[0]; b1N = Br[192];
    }

    for (int it = 0; it < niter; ++it) {
        const float4 a = aN;
        const float f0 = a0N + b0N, f1 = a1N + b1N;
        const unsigned code = __float_as_uint(a.w);
        const int i = q0 + it * 4 + ns;
        const bool valid = (i < q1);

        // prefetch next iteration
        if (it + 1 < niter) {
            const int ic = min(q0 + (it + 1) * 4 + ns, q1 - 1);
            aN = aux[ic];
            const unsigned cn = __float_as_uint(aN.w);
            const float* Ar = A + (((cn >> 24) * 100 + ((cn >> 17) & 127u)) << 6) + jj;
            const float* Br = B + (((cn >> 24) * 3 + ((cn >> 15) & 3u)) << 6) + jj;
            a0N = Ar[0]; a1N = Ar[6400]; b0N = Br[0]; b1N = Br[192];
        }

        const float fr = (float)(code & 32767u) * 3.0517578125e-5f;  // /32768
        float xwv = fmaf(fr, f1 - f0, f0);
        xwv = valid ? xwv : 0.f;

        const float ux = a.x, uy = a.y, uz = a.z;
        const float s3 = 1.7320508075688772f, s5 = 2.2360679774997896f, s7 = 2.6457513110645907f;

        if (l == 0) {
            acc[0] += xwv;
        } else if (l == 1) {
            acc[0] = fmaf(xwv, s3 * ux, acc[0]);
            acc[1] = fmaf(xwv, s3 * uy, acc[1]);
            acc[2] = fmaf(xwv, s3 * uz, acc[2]);
        } else if (l == 2) {
            const float y2 = uy * uy, x2z2 = ux * ux + uz * uz;
            const float s20 = s3 * ux * uz;
            const float s21 = s3 * ux * uy;
            const float s22 = y2 - 0.5f * x2z2;
            const float s23 = s3 * uy * uz;
            const float s24 = 0.5f * s3 * (uz * uz - ux * ux);
            const float xs = xwv * s5;
            acc[0] = fmaf(xs, s20, acc[0]);
            acc[1] = fmaf(xs, s21, acc[1]);
            acc[2] = fmaf(xs, s22, acc[2]);
            acc[3] = fmaf(xs, s23, acc[3]);
            acc[4] = fmaf(xs, s24, acc[4]);
        } else {
            const float y2 = uy * uy, x2z2 = ux * ux + uz * uz;
            const float s20 = s3 * ux * uz;
            const float s24 = 0.5f * s3 * (uz * uz - ux * ux);
            const float c56 = 0.9128709291752769f;  // sqrt(5/6)
            const float c38 = 0.6123724356957945f;  // sqrt(3/8)
            const float r4 = 4.f * y2 - x2z2;
            const float s30 = c56 * (s20 * uz + s24 * ux);
            const float s31 = s5 * s20 * uy;
            const float s32 = c38 * r4 * ux;
            const float s33 = 0.5f * uy * (2.f * y2 - 3.f * x2z2);
            const float s34 = c38 * uz * r4;
            const float s35 = s5 * s24 * uy;
            const float s36 = c56 * (s24 * uz - s20 * ux);
            const float xs = xwv * s7;
            acc[0] = fmaf(xs, s30, acc[0]);
            acc[1] = fmaf(xs, s31, acc[1]);
            acc[2] = fmaf(xs, s32, acc[2]);
            acc[3] = fmaf(xs, s33, acc[3]);
            acc[4] = fmaf(xs, s34, acc[4]);
            acc[5] = fmaf(xs, s35, acc[5]);
            acc[6] = fmaf(xs, s36, acc[6]);
        }
    }

    // deposit: row = ns; wave l writes its disjoint column range
    const int nl = 2 * l + 1;
    const int off = (l == 0 ? 0 : (l == 1 ? 16 : (l == 2 ? 64 : 144)));
    const int base = off + wi * nl;
#pragma unroll
    for (int k = 0; k < 7; ++k)
        if (k < nl) red[ns * 257 + base + k] = acc[k];
    __syncthreads();

    if (threadIdx.x < 256) {
        float s = 0.f;
#pragma unroll
        for (int ww = 0; ww < 4; ++ww) s += red[ww * 257 + threadIdx.x];
        partials[blockIdx.x * 256 + threadIdx.x] = s;
    }
}

// ---------------------------------------------------------------------------
// reduce: out[g][t] = (1/cnt) * sum_c partials[g*CH+c][t]
// ---------------------------------------------------------------------------
__global__ __launch_bounds__(256) void reduce(
    const float* __restrict__ partials, const int* __restrict__ seg,
    float* __restrict__ out)
{
    const int g = blockIdx.x;
    const int t = threadIdx.x;
    const int cnt = seg[g + 1] - seg[g];
    float s = 0.f;
#pragma unroll
    for (int c = 0; c < CH; ++c)
        s += partials[(g * CH + c) * 256 + t];
    out[g * 256 + t] = s / (float)max(cnt, 1);
}

// ---------------------------------------------------------------------------
static double silu_c_host()
{
    const int n = 200001;
    const double h = 24.0 / 200000.0;
    double sum = 0.0, prev = 0.0;
    for (int i = 0; i < n; ++i) {
        const double z = -12.0 + h * (double)i;
        const double pdf = exp(-0.5 * z * z) * 0.3989422804014327;
        const double s = z / (1.0 + exp(-z));
        const double f = s * s * pdf;
        if (i) sum += prev + f;
        prev = f;
    }
    sum *= 0.5 * h;
    return 1.0 / sqrt(sum);
}

extern "C" void kernel_launch(void* const* d_in, const int* in_sizes, int n_in,
                              void* d_out, int out_size, void* d_ws, size_t ws_size,
                              hipStream_t stream)
{
    const float* pos     = (const float*)d_in[0];
    const int*   xz      = (const int*)d_in[1];
    const int*   mol     = (const int*)d_in[2];
    const int*   batch   = (const int*)d_in[3];
    const float* emb_z   = (const float*)d_in[4];
    const float* emb_mol = (const float*)d_in[5];
    const float* W1      = (const float*)d_in[6];
    const float* W2      = (const float*)d_in[7];
    float* out = (float*)d_out;

    // workspace layout (floats): A | B | seg(1024 ints) | aux | partials ~= 9.9 MB
    float*  Abuf  = (float*)d_ws;
    float*  Bbuf  = Abuf + A_ELEMS;
    int*    seg   = (int*)(Bbuf + B_ELEMS);
    float4* aux   = (float4*)((float*)seg + 1024);
    float*  parts = (float*)aux + 4 * N_NODES;

    static const float SILU_C_F = (float)silu_c_host();

    build_AB<<<NB_ALL, 256, 0, stream>>>(emb_z, emb_mol, W2, W1, batch,
                                         pos, xz, mol, Abuf, Bbuf, seg, aux, SILU_C_F);
    seg_xw<<<G_SEG * CH, 256, 0, stream>>>(aux, seg, Abuf, Bbuf, parts);
    reduce<<<G_SEG, 256, 0, stream>>>(parts, seg, out);
}

// Round 13
// 39.522 us; speedup vs baseline: 1.7129x; 1.0023x over previous
//
#include <hip/hip_runtime.h>
#include <math.h>

#define N_NODES 65536
#define G_SEG   512
#define NE      256                  // L-grid intervals over [0,10] for xw lerp

// K1 roles
#define NB_HS 33                     // hs table 257x32
#define NB_Q  128                    // Q[z][m][j]: block = (m, z-quarter)
#define NB_QM 32                     // Qm[mo][m][j]: block = m
#define NB_S  3                      // seg bounds
#define NB_P0 (N_NODES / 256)        // 256: per-node aux
#define NB_K1 (NB_HS + NB_Q + NB_QM + NB_S + NB_P0)   // 452

// K2 roles
#define NB_A  1700                   // 17 e-tiles x 100 z
#define NB_B2 257                    // B rows
#define NB_K2 (NB_A + NB_B2)

#define A_ELEMS  (257 * 100 * 64)    // 6.58 MB
#define B_ELEMS  (257 * 3 * 64)
#define Q_ELEMS  (100 * 32 * 64)     // 800 KB
#define QM_ELEMS (3 * 32 * 64)
#define HS_ELEMS (257 * 32)

// ---------------------------------------------------------------------------
// K1: five independent light roles. W2 is read ~once (Q-role stages one m-row
// per block in LDS; 4 z-quarter blocks per m => 2 MB total, vs 131 MB before).
// ---------------------------------------------------------------------------
__global__ __launch_bounds__(256) void prep1(
    const float* __restrict__ emb_z, const float* __restrict__ emb_mol,
    const float* __restrict__ W2, const float* __restrict__ W1,
    const int* __restrict__ batch,
    const float* __restrict__ pos, const int* __restrict__ xz,
    const int* __restrict__ mol,
    float* __restrict__ Q, float* __restrict__ Qm, float* __restrict__ hs,
    int* __restrict__ seg, float4* __restrict__ aux, float silu_c)
{
    __shared__ float w2s[64 * 49];   // [cc][u], stride 49 kills bank conflicts
    __shared__ float ezq[1200];      // 25 z x 48 u

    const int b = blockIdx.x;
    const int t = threadIdx.x;

    if (b < NB_HS) {
        // hs[e][m] = scale * silu_c * silu( sum_k basis_k(e) * W1[k][m] )
        const int tid = b * 256 + t;
        if (tid >= HS_ELEMS) return;
        const int e = tid >> 5, m = tid & 31;
        const float L = (float)e * (10.f / (float)NE);
        const float c = 8.4335412f;     // 1.14136 * exp(2)
        float p = 0.f;
#pragma unroll
        for (int k = 0; k < 10; ++k) {
            const float a  = 1.1f * L - (float)k;
            const float bb = (float)(k + 2) - 1.1f * L;
            // exp(-1/a)*exp(-1/b) = exp(-2/(ab)) since a+b == 2
            const float bas = (a > 0.f && bb > 0.f) ? c * __expf(-2.f / (a * bb)) : 0.f;
            p = fmaf(bas, W1[k * 32 + m], p);
        }
        const float scale = 0.02209708691207961f;   // 1/sqrt(2048), folded here
        hs[tid] = scale * silu_c * p / (1.f + __expf(-p));
    } else if (b < NB_HS + NB_Q) {
        // Q[(zq*25+zl)][m][cc] = sum_{u<48} emb_z[z][u] * W2[m][l*1024+u*16+wi]
        const int q  = b - NB_HS;
        const int m  = q >> 2;
        const int zq = q & 3;
        for (int p = t; p < 3072; p += 256) {
            const int l = p / 768, r = p - l * 768;       // r = u*16+wi, u<48
            w2s[((l * 16) + (r & 15)) * 49 + (r >> 4)] = W2[m * 4096 + l * 1024 + r];
        }
        for (int p = t; p < 1200; p += 256) ezq[p] = emb_z[zq * 1200 + p];
        __syncthreads();

        const int zg = t >> 6, cc = t & 63;
#pragma unroll
        for (int zi = 0; zi < 7; ++zi) {
            const int zl = zg + 4 * zi;                   // wave-uniform
            if (zl < 25) {
                float a0 = 0.f, a1 = 0.f, a2 = 0.f, a3 = 0.f;
#pragma unroll
                for (int u = 0; u < 48; u += 4) {
                    a0 = fmaf(ezq[zl * 48 + u + 0], w2s[cc * 49 + u + 0], a0);
                    a1 = fmaf(ezq[zl * 48 + u + 1], w2s[cc * 49 + u + 1], a1);
                    a2 = fmaf(ezq[zl * 48 + u + 2], w2s[cc * 49 + u + 2], a2);
                    a3 = fmaf(ezq[zl * 48 + u + 3], w2s[cc * 49 + u + 3], a3);
                }
                Q[(((zq * 25 + zl) * 32 + m) << 6) + cc] = (a0 + a1) + (a2 + a3);
            }
        }
    } else if (b < NB_HS + NB_Q + NB_QM) {
        // Qm[mo][m][j] = sum_{v<16} emb_mol[mo][v] * W2[m][l*1024+(48+v)*16+wi]
        const int m = b - (NB_HS + NB_Q);
        if (t < 192) {
            const int mo = t >> 6, j = t & 63;
            const float* wp = W2 + m * 4096 + (j >> 4) * 1024 + 768 + (j & 15);
            float acc = 0.f;
#pragma unroll
            for (int v = 0; v < 16; ++v)
                acc = fmaf(emb_mol[mo * 16 + v], wp[v * 16], acc);
            Qm[((mo * 32 + m) << 6) + j] = acc;
        }
    } else if (b < NB_HS + NB_Q + NB_QM + NB_S) {
        const int g = (b - NB_HS - NB_Q - NB_QM) * 256 + t;
        if (g > G_SEG) return;
        int lo = 0, hi = N_NODES;
        while (lo < hi) {
            const int mid = (lo + hi) >> 1;
            if (batch[mid] < g) lo = mid + 1; else hi = mid;
        }
        seg[g] = lo;
    } else {
        const int i = (b - NB_HS - NB_Q - NB_QM - NB_S) * 256 + t;
        const float px = pos[3 * i], py = pos[3 * i + 1], pz = pos[3 * i + 2];
        const int z  = xz[i];
        const int mo = mol[i];
        const float Lsq = px * px + py * py + pz * pz;
        const float rinv = __builtin_amdgcn_rsqf(Lsq);
        const float L = Lsq * rinv;
        const float tt = fminf(L * ((float)NE / 10.0f), 255.999f);
        const int e = (int)tt;
        const int fr15 = min((int)((tt - (float)e) * 32768.f), 32767);
        float4 a;
        a.x = px * rinv; a.y = py * rinv; a.z = pz * rinv;
        a.w = __uint_as_float(((unsigned)e << 24) | ((unsigned)z << 17) |
                              ((unsigned)mo << 15) | (unsigned)fr15);
        aux[i] = a;
    }
}

// ---------------------------------------------------------------------------
// K2: A[e][z][j] = sum_m hs[e][m] * Q[z][m][j]  (blocks 0..1699: 17 e-tiles x z)
//     B[e][mo][j] = sum_m hs[e][m] * Qm[mo][m][j]  (blocks 1700..1956)
// Q column held in registers; e wave-uniform -> hs reads are scalar loads.
// ---------------------------------------------------------------------------
__global__ __launch_bounds__(256) void build_AB2(
    const float* __restrict__ Q, const float* __restrict__ Qm,
    const float* __restrict__ hs,
    float* __restrict__ A, float* __restrict__ B)
{
    const int b = blockIdx.x;
    const int t = threadIdx.x;
    const int j = t & 63;
    const int er = __builtin_amdgcn_readfirstlane(t >> 6);

    if (b < NB_A) {
        const int et = b / 100;
        const int z  = b - et * 100;
        float Qr[32];
        const float* Qp = Q + ((z * 32) << 6) + j;
#pragma unroll
        for (int m = 0; m < 32; ++m) Qr[m] = Qp[m << 6];

        const int e0 = et * 16;
#pragma unroll
        for (int p4 = 0; p4 < 4; ++p4) {
            const int e = e0 + er + 4 * p4;               // wave-uniform
            if (e < 257) {
                const float* hp = hs + e * 32;
                float a0 = 0.f, a1 = 0.f, a2 = 0.f, a3 = 0.f;
#pragma unroll
                for (int m = 0; m < 32; m += 4) {
                    a0 = fmaf(hp[m + 0], Qr[m + 0], a0);
                    a1 = fmaf(hp[m + 1], Qr[m + 1], a1);
                    a2 = fmaf(hp[m + 2], Qr[m + 2], a2);
                    a3 = fmaf(hp[m + 3], Qr[m + 3], a3);
                }
                A[((e * 100 + z) << 6) + j] = (a0 + a1) + (a2 + a3);
            }
        }
    } else {
        const int e  = b - NB_A;
        const int mo = t >> 6;
        if (mo < 3) {
            const float* Qp = Qm + ((mo * 32) << 6) + j;
            const float* hp = hs + e * 32;
            float acc = 0.f;
#pragma unroll
            for (int m = 0; m < 32; ++m)
                acc = fmaf(hp[m], Qp[m << 6], acc);
            B[((e * 3 + mo) << 6) + j] = acc;
        }
    }
}

// ---------------------------------------------------------------------------
// K3: one block per segment, 512 thr = 8 waves. Wave w: l = w&3 (wave-uniform
// SH), half = w>>2 (node range split). lane = ns*16+wi covers 4 nodes/iter.
// red[8][257]: row = half*4+ns; the four l-waves write disjoint column ranges.
// Direct mean write -- no partials, no reduce kernel, no atomics.
// ---------------------------------------------------------------------------
__global__ __launch_bounds__(512) void seg_mean(
    const float4* __restrict__ aux, const int* __restrict__ seg,
    const float* __restrict__ A, const float* __restrict__ B,
    float* __restrict__ out)
{
    __shared__ float red[8 * 257];

    const int g  = blockIdx.x;
    const int s0 = seg[g], s1 = seg[g + 1];
    const int cnt = s1 - s0;

    const int w8   = __builtin_amdgcn_readfirstlane(threadIdx.x >> 6);  // 0..7
    const int l    = w8 & 3;
    const int hf   = w8 >> 2;
    const int lane = threadIdx.x & 63;
    const int ns   = lane >> 4;
    const int wi   = lane & 15;
    const int jj   = l * 16 + wi;

    const int mid = s0 + ((cnt + 1) >> 1);
    const int q0 = hf ? mid : s0;
    const int q1 = hf ? s1 : mid;

    float acc[7];
#pragma unroll
    for (int k = 0; k < 7; ++k) acc[k] = 0.f;

    const int niter = (q1 - q0 + 3) >> 2;   // wave-uniform

    float4 aN = make_float4(0.f, 0.f, 1.f, __uint_as_float(0u));
    float a0N = 0.f, a1N = 0.f, b0N = 0.f, b1N = 0.f;
    if (niter > 0) {
        const int ic = min(q0 + ns, q1 - 1);
        aN = aux[ic];
        const unsigned cd = __float_as_uint(aN.w);
        const float* Ar = A + (((cd >> 24) * 100 + ((cd >> 17) & 127u)) << 6) + jj;
        const float* Br = B + (((cd >> 24) * 3 + ((cd >> 15) & 3u)) << 6) + jj;
        a0N = Ar[0]; a1N = Ar[6400]; b0N = Br[0]; b1N = Br[192];
    }

    for (int it = 0; it < niter; ++it) {
        const float4 a = aN;
        const float f0 = a0N + b0N, f1 = a1N + b1N;
        const unsigned code = __float_as_uint(a.w);
        const int i = q0 + it * 4 + ns;
        const bool valid = (i < q1);

        if (it + 1 < niter) {
            const int ic = min(q0 + (it + 1) * 4 + ns, q1 - 1);
            aN = aux[ic];
            const unsigned cn = __float_as_uint(aN.w);
            const float* Ar = A + (((cn >> 24) * 100 + ((cn >> 17) & 127u)) << 6) + jj;
            const float* Br = B + (((cn >> 24) * 3 + ((cn >> 15) & 3u)) << 6) + jj;
            a0N = Ar[0]; a1N = Ar[6400]; b0N = Br[0]; b1N = Br[192];
        }

        const float fr = (float)(code & 32767u) * 3.0517578125e-5f;  // /32768
        float xwv = fmaf(fr, f1 - f0, f0);
        xwv = valid ? xwv : 0.f;

        const float ux = a.x, uy = a.y, uz = a.z;
        const float s3 = 1.7320508075688772f, s5 = 2.2360679774997896f, s7 = 2.6457513110645907f;

        if (l == 0) {
            acc[0] += xwv;
        } else if (l == 1) {
            acc[0] = fmaf(xwv, s3 * ux, acc[0]);
            acc[1] = fmaf(xwv, s3 * uy, acc[1]);
            acc[2] = fmaf(xwv, s3 * uz, acc[2]);
        } else if (l == 2) {
            const float y2 = uy * uy, x2z2 = ux * ux + uz * uz;
            const float s20 = s3 * ux * uz;
            const float s21 = s3 * ux * uy;
            const float s22 = y2 - 0.5f * x2z2;
            const float s23 = s3 * uy * uz;
            const float s24 = 0.5f * s3 * (uz * uz - ux * ux);
            const float xs = xwv * s5;
            acc[0] = fmaf(xs, s20, acc[0]);
            acc[1] = fmaf(xs, s21, acc[1]);
            acc[2] = fmaf(xs, s22, acc[2]);
            acc[3] = fmaf(xs, s23, acc[3]);
            acc[4] = fmaf(xs, s24, acc[4]);
        } else {
            const float y2 = uy * uy, x2z2 = ux * ux + uz * uz;
            const float s20 = s3 * ux * uz;
            const float s24 = 0.5f * s3 * (uz * uz - ux * ux);
            const float c56 = 0.9128709291752769f;  // sqrt(5/6)
            const float c38 = 0.6123724356957945f;  // sqrt(3/8)
            const float r4 = 4.f * y2 - x2z2;
            const float s30 = c56 * (s20 * uz + s24 * ux);
            const float s31 = s5 * s20 * uy;
            const float s32 = c38 * r4 * ux;
            const float s33 = 0.5f * uy * (2.f * y2 - 3.f * x2z2);
            const float s34 = c38 * uz * r4;
            const float s35 = s5 * s24 * uy;
            const float s36 = c56 * (s24 * uz - s20 * ux);
            const float xs = xwv * s7;
            acc[0] = fmaf(xs, s30, acc[0]);
            acc[1] = fmaf(xs, s31, acc[1]);
            acc[2] = fmaf(xs, s32, acc[2]);
            acc[3] = fmaf(xs, s33, acc[3]);
            acc[4] = fmaf(xs, s34, acc[4]);
            acc[5] = fmaf(xs, s35, acc[5]);
            acc[6] = fmaf(xs, s36, acc[6]);
        }
    }

    const int nl = 2 * l + 1;
    const int off = (l == 0 ? 0 : (l == 1 ? 16 : (l == 2 ? 64 : 144)));
    const int base = off + wi * nl;
#pragma unroll
    for (int k = 0; k < 7; ++k)
        if (k < nl) red[(hf * 4 + ns) * 257 + base + k] = acc[k];
    __syncthreads();

    if (threadIdx.x < 256) {
        float s = 0.f;
#pragma unroll
        for (int ww = 0; ww < 8; ++ww) s += red[ww * 257 + threadIdx.x];
        out[g * 256 + threadIdx.x] = s / (float)max(cnt, 1);
    }
}

// ---------------------------------------------------------------------------
static double silu_c_host()
{
    const int n = 200001;
    const double h = 24.0 / 200000.0;
    double sum = 0.0, prev = 0.0;
    for (int i = 0; i < n; ++i) {
        const double z = -12.0 + h * (double)i;
        const double pdf = exp(-0.5 * z * z) * 0.3989422804014327;
        const double s = z / (1.0 + exp(-z));
        const double f = s * s * pdf;
        if (i) sum += prev + f;
        prev = f;
    }
    sum *= 0.5 * h;
    return 1.0 / sqrt(sum);
}

extern "C" void kernel_launch(void* const* d_in, const int* in_sizes, int n_in,
                              void* d_out, int out_size, void* d_ws, size_t ws_size,
                              hipStream_t stream)
{
    const float* pos     = (const float*)d_in[0];
    const int*   xz      = (const int*)d_in[1];
    const int*   mol     = (const int*)d_in[2];
    const int*   batch   = (const int*)d_in[3];
    const float* emb_z   = (const float*)d_in[4];
    const float* emb_mol = (const float*)d_in[5];
    const float* W1      = (const float*)d_in[6];
    const float* W2      = (const float*)d_in[7];
    float* out = (float*)d_out;

    // workspace (floats): aux | A | B | Q | Qm | hs | seg  ~= 8.7 MB
    float4* aux  = (float4*)d_ws;
    float*  Abuf = (float*)d_ws + 4 * N_NODES;
    float*  Bbuf = Abuf + A_ELEMS;
    float*  Qbuf = Bbuf + B_ELEMS;
    float*  Qmb  = Qbuf + Q_ELEMS;
    float*  hsb  = Qmb + QM_ELEMS;
    int*    seg  = (int*)(hsb + HS_ELEMS);

    static const float SILU_C_F = (float)silu_c_host();

    prep1<<<NB_K1, 256, 0, stream>>>(emb_z, emb_mol, W2, W1, batch,
                                     pos, xz, mol, Qbuf, Qmb, hsb, seg, aux, SILU_C_F);
    build_AB2<<<NB_K2, 256, 0, stream>>>(Qbuf, Qmb, hsb, Abuf, Bbuf);
    seg_mean<<<G_SEG, 512, 0, stream>>>(aux, seg, Abuf, Bbuf, out);
}

// Round 14
// 33.716 us; speedup vs baseline: 2.0079x; 1.1722x over previous
//
#include <hip/hip_runtime.h>
#include <math.h>

#define N_NODES 65536
#define G_SEG   512
#define NE      256                  // L-grid intervals over [0,10] for xw lerp

// K1 roles
#define NB_HS 33                     // hs table 257x32
#define NB_Q  128                    // Q[z][m][j]: block = (m, z-quarter)
#define NB_QM 32                     // Qm[mo][m][j]: block = m
#define NB_S  3                      // seg bounds
#define NB_P0 (N_NODES / 256)        // 256: per-node aux
#define NB_K1 (NB_HS + NB_Q + NB_QM + NB_S + NB_P0)   // 452

// K2 roles
#define NB_A  1700                   // 17 e-tiles x 100 z
#define NB_B2 257                    // B rows
#define NB_K2 (NB_A + NB_B2)

#define A_ELEMS  (257 * 100 * 64)    // 6.58 MB
#define B_ELEMS  (257 * 3 * 64)
#define Q_ELEMS  (100 * 32 * 64)     // 800 KB
#define QM_ELEMS (3 * 32 * 64)
#define HS_ELEMS (257 * 32)

// ---------------------------------------------------------------------------
// K1: five independent light roles.  (unchanged from round 13)
// ---------------------------------------------------------------------------
__global__ __launch_bounds__(256) void prep1(
    const float* __restrict__ emb_z, const float* __restrict__ emb_mol,
    const float* __restrict__ W2, const float* __restrict__ W1,
    const int* __restrict__ batch,
    const float* __restrict__ pos, const int* __restrict__ xz,
    const int* __restrict__ mol,
    float* __restrict__ Q, float* __restrict__ Qm, float* __restrict__ hs,
    int* __restrict__ seg, float4* __restrict__ aux, float silu_c)
{
    __shared__ float w2s[64 * 49];   // [cc][u], stride 49 kills bank conflicts
    __shared__ float ezq[1200];      // 25 z x 48 u

    const int b = blockIdx.x;
    const int t = threadIdx.x;

    if (b < NB_HS) {
        const int tid = b * 256 + t;
        if (tid >= HS_ELEMS) return;
        const int e = tid >> 5, m = tid & 31;
        const float L = (float)e * (10.f / (float)NE);
        const float c = 8.4335412f;     // 1.14136 * exp(2)
        float p = 0.f;
#pragma unroll
        for (int k = 0; k < 10; ++k) {
            const float a  = 1.1f * L - (float)k;
            const float bb = (float)(k + 2) - 1.1f * L;
            // exp(-1/a)*exp(-1/b) = exp(-2/(ab)) since a+b == 2
            const float bas = (a > 0.f && bb > 0.f) ? c * __expf(-2.f / (a * bb)) : 0.f;
            p = fmaf(bas, W1[k * 32 + m], p);
        }
        const float scale = 0.02209708691207961f;   // 1/sqrt(2048), folded here
        hs[tid] = scale * silu_c * p / (1.f + __expf(-p));
    } else if (b < NB_HS + NB_Q) {
        const int q  = b - NB_HS;
        const int m  = q >> 2;
        const int zq = q & 3;
        for (int p = t; p < 3072; p += 256) {
            const int l = p / 768, r = p - l * 768;       // r = u*16+wi, u<48
            w2s[((l * 16) + (r & 15)) * 49 + (r >> 4)] = W2[m * 4096 + l * 1024 + r];
        }
        for (int p = t; p < 1200; p += 256) ezq[p] = emb_z[zq * 1200 + p];
        __syncthreads();

        const int zg = t >> 6, cc = t & 63;
#pragma unroll
        for (int zi = 0; zi < 7; ++zi) {
            const int zl = zg + 4 * zi;                   // wave-uniform
            if (zl < 25) {
                float a0 = 0.f, a1 = 0.f, a2 = 0.f, a3 = 0.f;
#pragma unroll
                for (int u = 0; u < 48; u += 4) {
                    a0 = fmaf(ezq[zl * 48 + u + 0], w2s[cc * 49 + u + 0], a0);
                    a1 = fmaf(ezq[zl * 48 + u + 1], w2s[cc * 49 + u + 1], a1);
                    a2 = fmaf(ezq[zl * 48 + u + 2], w2s[cc * 49 + u + 2], a2);
                    a3 = fmaf(ezq[zl * 48 + u + 3], w2s[cc * 49 + u + 3], a3);
                }
                Q[(((zq * 25 + zl) * 32 + m) << 6) + cc] = (a0 + a1) + (a2 + a3);
            }
        }
    } else if (b < NB_HS + NB_Q + NB_QM) {
        const int m = b - (NB_HS + NB_Q);
        if (t < 192) {
            const int mo = t >> 6, j = t & 63;
            const float* wp = W2 + m * 4096 + (j >> 4) * 1024 + 768 + (j & 15);
            float acc = 0.f;
#pragma unroll
            for (int v = 0; v < 16; ++v)
                acc = fmaf(emb_mol[mo * 16 + v], wp[v * 16], acc);
            Qm[((mo * 32 + m) << 6) + j] = acc;
        }
    } else if (b < NB_HS + NB_Q + NB_QM + NB_S) {
        const int g = (b - NB_HS - NB_Q - NB_QM) * 256 + t;
        if (g > G_SEG) return;
        int lo = 0, hi = N_NODES;
        while (lo < hi) {
            const int mid = (lo + hi) >> 1;
            if (batch[mid] < g) lo = mid + 1; else hi = mid;
        }
        seg[g] = lo;
    } else {
        const int i = (b - NB_HS - NB_Q - NB_QM - NB_S) * 256 + t;
        const float px = pos[3 * i], py = pos[3 * i + 1], pz = pos[3 * i + 2];
        const int z  = xz[i];
        const int mo = mol[i];
        const float Lsq = px * px + py * py + pz * pz;
        const float rinv = __builtin_amdgcn_rsqf(Lsq);
        const float L = Lsq * rinv;
        const float tt = fminf(L * ((float)NE / 10.0f), 255.999f);
        const int e = (int)tt;
        const int fr15 = min((int)((tt - (float)e) * 32768.f), 32767);
        float4 a;
        a.x = px * rinv; a.y = py * rinv; a.z = pz * rinv;
        a.w = __uint_as_float(((unsigned)e << 24) | ((unsigned)z << 17) |
                              ((unsigned)mo << 15) | (unsigned)fr15);
        aux[i] = a;
    }
}

// ---------------------------------------------------------------------------
// K2: A/B build.  (unchanged from round 13)
// ---------------------------------------------------------------------------
__global__ __launch_bounds__(256) void build_AB2(
    const float* __restrict__ Q, const float* __restrict__ Qm,
    const float* __restrict__ hs,
    float* __restrict__ A, float* __restrict__ B)
{
    const int b = blockIdx.x;
    const int t = threadIdx.x;
    const int j = t & 63;
    const int er = __builtin_amdgcn_readfirstlane(t >> 6);

    if (b < NB_A) {
        const int et = b / 100;
        const int z  = b - et * 100;
        float Qr[32];
        const float* Qp = Q + ((z * 32) << 6) + j;
#pragma unroll
        for (int m = 0; m < 32; ++m) Qr[m] = Qp[m << 6];

        const int e0 = et * 16;
#pragma unroll
        for (int p4 = 0; p4 < 4; ++p4) {
            const int e = e0 + er + 4 * p4;               // wave-uniform
            if (e < 257) {
                const float* hp = hs + e * 32;
                float a0 = 0.f, a1 = 0.f, a2 = 0.f, a3 = 0.f;
#pragma unroll
                for (int m = 0; m < 32; m += 4) {
                    a0 = fmaf(hp[m + 0], Qr[m + 0], a0);
                    a1 = fmaf(hp[m + 1], Qr[m + 1], a1);
                    a2 = fmaf(hp[m + 2], Qr[m + 2], a2);
                    a3 = fmaf(hp[m + 3], Qr[m + 3], a3);
                }
                A[((e * 100 + z) << 6) + j] = (a0 + a1) + (a2 + a3);
            }
        }
    } else {
        const int e  = b - NB_A;
        const int mo = t >> 6;
        if (mo < 3) {
            const float* Qp = Qm + ((mo * 32) << 6) + j;
            const float* hp = hs + e * 32;
            float acc = 0.f;
#pragma unroll
            for (int m = 0; m < 32; ++m)
                acc = fmaf(hp[m], Qp[m << 6], acc);
            B[((e * 3 + mo) << 6) + j] = acc;
        }
    }
}

// ---------------------------------------------------------------------------
// K3: one block per segment, 1024 thr = 16 waves (RESTORED R12 wave count).
// Wave w: l = w&3 (wave-uniform SH), qt = w>>2 (node-quarter). lane = ns*16+wi
// covers 4 nodes/iter. red[16][257]: row = qt*4+ns; the four l-waves write
// disjoint column ranges. Direct mean write -- no partials/reduce/atomics.
// ---------------------------------------------------------------------------
__global__ __launch_bounds__(1024) void seg_mean(
    const float4* __restrict__ aux, const int* __restrict__ seg,
    const float* __restrict__ A, const float* __restrict__ B,
    float* __restrict__ out)
{
    __shared__ float red[16 * 257];

    const int g  = blockIdx.x;
    const int s0 = seg[g], s1 = seg[g + 1];
    const int cnt = s1 - s0;

    const int w16  = __builtin_amdgcn_readfirstlane(threadIdx.x >> 6);  // 0..15
    const int l    = w16 & 3;
    const int qt   = w16 >> 2;
    const int lane = threadIdx.x & 63;
    const int ns   = lane >> 4;
    const int wi   = lane & 15;
    const int jj   = l * 16 + wi;

    const int q0 = s0 + ((cnt * qt) >> 2);
    const int q1 = s0 + ((cnt * (qt + 1)) >> 2);

    float acc[7];
#pragma unroll
    for (int k = 0; k < 7; ++k) acc[k] = 0.f;

    const int niter = (q1 - q0 + 3) >> 2;   // wave-uniform

    float4 aN = make_float4(0.f, 0.f, 1.f, __uint_as_float(0u));
    float a0N = 0.f, a1N = 0.f, b0N = 0.f, b1N = 0.f;
    if (niter > 0) {
        const int ic = min(q0 + ns, q1 - 1);
        aN = aux[ic];
        const unsigned cd = __float_as_uint(aN.w);
        const float* Ar = A + (((cd >> 24) * 100 + ((cd >> 17) & 127u)) << 6) + jj;
        const float* Br = B + (((cd >> 24) * 3 + ((cd >> 15) & 3u)) << 6) + jj;
        a0N = Ar[0]; a1N = Ar[6400]; b0N = Br[0]; b1N = Br[192];
    }

    for (int it = 0; it < niter; ++it) {
        const float4 a = aN;
        const float f0 = a0N + b0N, f1 = a1N + b1N;
        const unsigned code = __float_as_uint(a.w);
        const int i = q0 + it * 4 + ns;
        const bool valid = (i < q1);

        if (it + 1 < niter) {
            const int ic = min(q0 + (it + 1) * 4 + ns, q1 - 1);
            aN = aux[ic];
            const unsigned cn = __float_as_uint(aN.w);
            const float* Ar = A + (((cn >> 24) * 100 + ((cn >> 17) & 127u)) << 6) + jj;
            const float* Br = B + (((cn >> 24) * 3 + ((cn >> 15) & 3u)) << 6) + jj;
            a0N = Ar[0]; a1N = Ar[6400]; b0N = Br[0]; b1N = Br[192];
        }

        const float fr = (float)(code & 32767u) * 3.0517578125e-5f;  // /32768
        float xwv = fmaf(fr, f1 - f0, f0);
        xwv = valid ? xwv : 0.f;

        const float ux = a.x, uy = a.y, uz = a.z;
        const float s3 = 1.7320508075688772f, s5 = 2.2360679774997896f, s7 = 2.6457513110645907f;

        if (l == 0) {
            acc[0] += xwv;
        } else if (l == 1) {
            acc[0] = fmaf(xwv, s3 * ux, acc[0]);
            acc[1] = fmaf(xwv, s3 * uy, acc[1]);
            acc[2] = fmaf(xwv, s3 * uz, acc[2]);
        } else if (l == 2) {
            const float y2 = uy * uy, x2z2 = ux * ux + uz * uz;
            const float s20 = s3 * ux * uz;
            const float s21 = s3 * ux * uy;
            const float s22 = y2 - 0.5f * x2z2;
            const float s23 = s3 * uy * uz;
            const float s24 = 0.5f * s3 * (uz * uz - ux * ux);
            const float xs = xwv * s5;
            acc[0] = fmaf(xs, s20, acc[0]);
            acc[1] = fmaf(xs, s21, acc[1]);
            acc[2] = fmaf(xs, s22, acc[2]);
            acc[3] = fmaf(xs, s23, acc[3]);
            acc[4] = fmaf(xs, s24, acc[4]);
        } else {
            const float y2 = uy * uy, x2z2 = ux * ux + uz * uz;
            const float s20 = s3 * ux * uz;
            const float s24 = 0.5f * s3 * (uz * uz - ux * ux);
            const float c56 = 0.9128709291752769f;  // sqrt(5/6)
            const float c38 = 0.6123724356957945f;  // sqrt(3/8)
            const float r4 = 4.f * y2 - x2z2;
            const float s30 = c56 * (s20 * uz + s24 * ux);
            const float s31 = s5 * s20 * uy;
            const float s32 = c38 * r4 * ux;
            const float s33 = 0.5f * uy * (2.f * y2 - 3.f * x2z2);
            const float s34 = c38 * uz * r4;
            const float s35 = s5 * s24 * uy;
            const float s36 = c56 * (s24 * uz - s20 * ux);
            const float xs = xwv * s7;
            acc[0] = fmaf(xs, s30, acc[0]);
            acc[1] = fmaf(xs, s31, acc[1]);
            acc[2] = fmaf(xs, s32, acc[2]);
            acc[3] = fmaf(xs, s33, acc[3]);
            acc[4] = fmaf(xs, s34, acc[4]);
            acc[5] = fmaf(xs, s35, acc[5]);
            acc[6] = fmaf(xs, s36, acc[6]);
        }
    }

    const int nl = 2 * l + 1;
    const int off = (l == 0 ? 0 : (l == 1 ? 16 : (l == 2 ? 64 : 144)));
    const int base = off + wi * nl;
#pragma unroll
    for (int k = 0; k < 7; ++k)
        if (k < nl) red[(qt * 4 + ns) * 257 + base + k] = acc[k];
    __syncthreads();

    if (threadIdx.x < 256) {
        float s = 0.f;
#pragma unroll
        for (int ww = 0; ww < 16; ++ww) s += red[ww * 257 + threadIdx.x];
        out[g * 256 + threadIdx.x] = s / (float)max(cnt, 1);
    }
}

// ---------------------------------------------------------------------------
static double silu_c_host()
{
    const int n = 200001;
    const double h = 24.0 / 200000.0;
    double sum = 0.0, prev = 0.0;
    for (int i = 0; i < n; ++i) {
        const double z = -12.0 + h * (double)i;
        const double pdf = exp(-0.5 * z * z) * 0.3989422804014327;
        const double s = z / (1.0 + exp(-z));
        const double f = s * s * pdf;
        if (i) sum += prev + f;
        prev = f;
    }
    sum *= 0.5 * h;
    return 1.0 / sqrt(sum);
}

extern "C" void kernel_launch(void* const* d_in, const int* in_sizes, int n_in,
                              void* d_out, int out_size, void* d_ws, size_t ws_size,
                              hipStream_t stream)
{
    const float* pos     = (const float*)d_in[0];
    const int*   xz      = (const int*)d_in[1];
    const int*   mol     = (const int*)d_in[2];
    const int*   batch   = (const int*)d_in[3];
    const float* emb_z   = (const float*)d_in[4];
    const float* emb_mol = (const float*)d_in[5];
    const float* W1      = (const float*)d_in[6];
    const float* W2      = (const float*)d_in[7];
    float* out = (float*)d_out;

    // workspace (floats): aux | A | B | Q | Qm | hs | seg  ~= 8.7 MB
    float4* aux  = (float4*)d_ws;
    float*  Abuf = (float*)d_ws + 4 * N_NODES;
    float*  Bbuf = Abuf + A_ELEMS;
    float*  Qbuf = Bbuf + B_ELEMS;
    float*  Qmb  = Qbuf + Q_ELEMS;
    float*  hsb  = Qmb + QM_ELEMS;
    int*    seg  = (int*)(hsb + HS_ELEMS);

    static const float SILU_C_F = (float)silu_c_host();

    prep1<<<NB_K1, 256, 0, stream>>>(emb_z, emb_mol, W2, W1, batch,
                                     pos, xz, mol, Qbuf, Qmb, hsb, seg, aux, SILU_C_F);
    build_AB2<<<NB_K2, 256, 0, stream>>>(Qbuf, Qmb, hsb, Abuf, Bbuf);
    seg_mean<<<G_SEG, 1024, 0, stream>>>(aux, seg, Abuf, Bbuf, out);
}